// Round 7
// baseline (368.837 us; speedup 1.0000x reference)
//
#include <hip/hip_runtime.h>
#include <math.h>

#define M_ANCH   589824
#define NCLS     80
#define TOPK_N   1000
#define CAND_CAP 4096
#define NREP     16
#define NBIN     8192          /* 13-bit bins */
#define KSHIFT   19

#define SCALE_CLAMP_F 4.135166556742356f   /* log(1000/16) as f32 */
#define INV_IMG       (1.0f/2048.0f)

// ---------------- ws layout (bytes) ----------------
// [0,      524288)   hist replicas (16 x 8192 u32)  -- memset 0
// [524288, 524292)   cand count (u32)               -- memset 0
// [524292, 524296)   gbin (u32)                     -- memset 0
// [524296, 524300)   red ticket (u32)               -- memset 0
// [524300, 524304)   sup ticket (u32)               -- memset 0
// [524544, 557312)   cand keys (4096 u64)
// [557312, 573312)   boxes (1000 float4)
// [573312, 577312)   labels (1000 i32)
// [577312, 581312)   valid (1000 i32)
// [581376, 712448)   supT matrix WORD-MAJOR (16 x 1024 u64)
// [712704, 3072000)  mkeys (589824 u32, 16B-aligned)
// [3072000,3104768)  reduced hist (8192 u32)
#define WS_H1R     0
#define WS_CNT     524288
#define WS_GBIN    524292
#define WS_TICK1   524296
#define WS_TICK2   524300
#define WS_MEMSET  524304
#define WS_CAND    524544
#define WS_BOXES   557312
#define WS_LABELS  573312
#define WS_VALID   577312
#define WS_SUP     581376
#define WS_MKEYS   712704
#define WS_HRED    3072000

// monotone float->uint map (positive floats get top bit set)
__device__ __forceinline__ unsigned fmap(unsigned b) {
    return (b & 0x80000000u) ? ~b : (b | 0x80000000u);
}
__device__ __forceinline__ unsigned funmap(unsigned k) {
    return (k & 0x80000000u) ? (k ^ 0x80000000u) : ~k;
}

// K1 (Design B): dense-coalesced row-max. Block owns 256 rows = 80 KB
// contiguous; chunk-max staged in LDS stride-21; packed 16-bit histogram.
// BW-bound (~30-35 us): two different access designs (r4/r5) timed identical.
__global__ __launch_bounds__(256) void k_rowmax(const float* __restrict__ cls,
                                                unsigned* __restrict__ mkeys,
                                                unsigned* __restrict__ h1r) {
    __shared__ float    cmax[256 * 21];   // 21504 B, stride-21 padded
    __shared__ unsigned lh[NBIN / 2];     // 16384 B packed 2 bins/u32
    int t = threadIdx.x;
    for (int b = t; b < NBIN / 2; b += 256) lh[b] = 0;
    // (lh atomics only happen after the phase-1 barrier below)

    const float4* p = (const float4*)cls + (size_t)blockIdx.x * (256 * 20);
#pragma unroll
    for (int i = 0; i < 20; ++i) {
        float4 v = p[i * 256 + t];
        float c = fmaxf(fmaxf(v.x, v.y), fmaxf(v.z, v.w));
        int cid = i * 256 + t;
        int row = cid / 20;               // compiler magic-mul
        int j   = cid - row * 20;
        cmax[row * 21 + j] = c;
    }
    __syncthreads();

    // phase 2: one row per thread, conflict-free LDS reads (stride 21)
    const float* rp = &cmax[t * 21];
    float m = -INFINITY;
#pragma unroll
    for (int j = 0; j < 20; ++j) m = fmaxf(m, rp[j]);
    unsigned key = fmap(__float_as_uint(m));
    mkeys[blockIdx.x * 256 + t] = key;    // coalesced 1 KB/block
    unsigned bin = key >> KSHIFT;
    atomicAdd(&lh[bin >> 1], 1u << ((bin & 1) << 4));
    __syncthreads();

    unsigned rep = (blockIdx.x & (NREP - 1)) * NBIN;
    for (int b2 = t; b2 < NBIN / 2; b2 += 256) {
        unsigned c = lh[b2];
        unsigned c0 = c & 0xFFFFu, c1 = c >> 16;
        if (c0) atomicAdd(&h1r[rep + 2 * b2], c0);
        if (c1) atomicAdd(&h1r[rep + 2 * b2 + 1], c1);
    }
}

// K1b+K2 fused: parallel replica reduction (32 blocks) + last-block-ticket
// find. Each block fences its hred writes then takes a ticket; the 32nd
// block (all others' writes visible per release/acquire fence pairing)
// inlines the bin search for the 1000th-largest key. Threshold = B-1.
__global__ __launch_bounds__(256) void k_red_find(const unsigned* __restrict__ h1r,
                                                  unsigned* __restrict__ hred,
                                                  unsigned* __restrict__ ticket,
                                                  unsigned* __restrict__ gbin) {
    __shared__ unsigned hist[NBIN];       // 32 KiB (last block only)
    __shared__ unsigned csum[256];
    __shared__ unsigned amLast;
    int t = threadIdx.x;
    int b = blockIdx.x * 256 + t;         // 32*256 = 8192 bins
    unsigned s = 0;
#pragma unroll
    for (int r = 0; r < NREP; ++r) s += h1r[r * NBIN + b];
    hred[b] = s;
    __threadfence();                      // release hred before ticket
    __syncthreads();
    if (t == 0) amLast = (atomicAdd(ticket, 1u) == (NBIN / 256 - 1)) ? 1u : 0u;
    __syncthreads();
    if (!amLast) return;
    __threadfence();                      // acquire

    for (int i = t; i < NBIN; i += 256) hist[i] = hred[i];
    __syncthreads();
    {
        unsigned cs = 0;
        for (int k = 0; k < 32; ++k) cs += hist[t * 32 + k];
        csum[t] = cs;
    }
    __syncthreads();
    if (t == 0) {
        unsigned cum = 0, above = 0;
        int C = 0;
        for (int c = 255; c >= 0; --c) {
            if (cum + csum[c] >= TOPK_N || c == 0) { C = c; above = cum; break; }
            cum += csum[c];
        }
        int B = C * 32;
        unsigned cum2 = above;
        for (int b2 = C * 32 + 31; b2 >= C * 32; --b2) {
            cum2 += hist[b2];
            if (cum2 >= TOPK_N) { B = b2; break; }
            if (b2 == C * 32) B = b2;
        }
        *gbin = (B >= 1) ? (unsigned)(B - 1) : 0u;
    }
}

// K3: gather candidates above threshold as (score_bits<<32)|~idx.
__global__ __launch_bounds__(256) void k_gather(const uint4* __restrict__ mk4,
                                                const unsigned* __restrict__ gbin,
                                                unsigned* __restrict__ cnt,
                                                unsigned long long* __restrict__ cand) {
    int tid = blockIdx.x * 256 + threadIdx.x;
    unsigned gb = *gbin;
    uint4 a = mk4[tid * 2];
    uint4 b4 = mk4[tid * 2 + 1];
    unsigned keys[8] = {a.x, a.y, a.z, a.w, b4.x, b4.y, b4.z, b4.w};
    int lc = 0;
    unsigned sel[8];
#pragma unroll
    for (int q = 0; q < 8; ++q)
        if ((keys[q] >> KSHIFT) >= gb) sel[lc++] = (unsigned)q;
    if (lc) {
        unsigned base = atomicAdd(cnt, (unsigned)lc);
        for (int q = 0; q < lc; ++q) {
            unsigned pos = base + (unsigned)q;
            if (pos < CAND_CAP) {
                unsigned i = (unsigned)tid * 8u + sel[q];
                float m = __uint_as_float(funmap(keys[sel[q]]));
                // emulate np float32 sigmoid pipeline (correctly-rounded exp):
                float e = (float)exp(-(double)m);
                float sc = 1.0f / (1.0f + e);
                cand[pos] = ((unsigned long long)__float_as_uint(sc) << 32)
                            | (unsigned)(~i);
            }
        }
    }
}

// K4: rank-by-count (keys unique) + direct decode into output slot.
__global__ __launch_bounds__(256) void k_rank_decode(const unsigned* __restrict__ cnt,
                                                     const unsigned long long* __restrict__ cand,
                                                     const float* __restrict__ cls,
                                                     const float* __restrict__ reg,
                                                     const float* __restrict__ anch,
                                                     float* __restrict__ out,
                                                     float4* __restrict__ boxes_ws,
                                                     int* __restrict__ lab_ws,
                                                     int* __restrict__ val_ws) {
    __shared__ unsigned long long sh[CAND_CAP];   // 32 KiB
    int t = threadIdx.x;
    unsigned n = *cnt;
    if (n > CAND_CAP) n = CAND_CAP;
    for (int k = t; k < (int)n; k += 256) sh[k] = cand[k];
    __syncthreads();
    int k = blockIdx.x * 256 + t;
    if (k >= (int)n) return;
    unsigned long long key = sh[k];
    int rank = 0;
    for (int j = 0; j < (int)n; ++j) rank += (sh[j] > key) ? 1 : 0;
    if (rank >= TOPK_N) return;
    int r = rank;
    unsigned idx = ~(unsigned)(key & 0xFFFFFFFFull);
    float sc = __uint_as_float((unsigned)(key >> 32));
    // label = argmax (first max wins, matching np.argmax), float4 loads
    const float4* rowp = (const float4*)(cls + (size_t)idx * NCLS);
    float best = -INFINITY;
    int lbl = 0;
#pragma unroll
    for (int c4 = 0; c4 < 20; ++c4) {
        float4 v = rowp[c4];
        if (v.x > best) { best = v.x; lbl = c4 * 4; }
        if (v.y > best) { best = v.y; lbl = c4 * 4 + 1; }
        if (v.z > best) { best = v.z; lbl = c4 * 4 + 2; }
        if (v.w > best) { best = v.w; lbl = c4 * 4 + 3; }
    }
    float4 rg = ((const float4*)reg)[idx];
    float4 an = ((const float4*)anch)[idx];
    float ox = fminf(fmaxf(rg.x * an.z, -32.0f), 32.0f);
    float oy = fminf(fmaxf(rg.y * an.w, -32.0f), 32.0f);
    float cx = an.x + ox, cy = an.y + oy;
    float w = an.z * expf(fminf(rg.z, SCALE_CLAMP_F));
    float h = an.w * expf(fminf(rg.w, SCALE_CLAMP_F));
    float x1 = fminf(fmaxf((cx - 0.5f * w) * INV_IMG, 0.0f), 1.0f);
    float y1 = fminf(fmaxf((cy - 0.5f * h) * INV_IMG, 0.0f), 1.0f);
    float x2 = fminf(fmaxf((cx + 0.5f * w) * INV_IMG, 0.0f), 1.0f);
    float y2 = fminf(fmaxf((cy + 0.5f * h) * INV_IMG, 0.0f), 1.0f);
    out[r * 4 + 0] = x1;
    out[r * 4 + 1] = y1;
    out[r * 4 + 2] = x2;
    out[r * 4 + 3] = y2;
    out[4 * TOPK_N + r] = sc;
    out[5 * TOPK_N + r] = (float)lbl;
    boxes_ws[r] = make_float4(x1, y1, x2, y2);
    lab_ws[r] = lbl;
    val_ws[r] = (sc >= 0.05f) ? 1 : 0;
}

// K5+K6 fused: suppression matrix (word-major supT[w*1024+i], lower
// triangle, 250 blocks x 4 rows) + last-block-ticket NMS on wave 0.
__global__ __launch_bounds__(256) void k_sup_nms(const float4* __restrict__ boxes,
                                                 const int* __restrict__ labs,
                                                 unsigned long long* __restrict__ supT,
                                                 unsigned* __restrict__ ticket,
                                                 const int* __restrict__ val,
                                                 float* __restrict__ out_keep) {
    __shared__ unsigned amLast;
    int t = threadIdx.x;
    int i = blockIdx.x * 4 + (t >> 6);
    int lane = t & 63;
    if (i < TOPK_N) {
        int cmax = i >> 6;
        float4 bi = boxes[i];
        float ai = (bi.z - bi.x) * (bi.w - bi.y);
        int li = labs[i];
        for (int c = 0; c <= cmax; ++c) {
            int j = c * 64 + lane;
            bool bit = false;
            if (j < TOPK_N) {
                float4 bj = boxes[j];
                float aj = (bj.z - bj.x) * (bj.w - bj.y);
                float xx1 = fmaxf(bi.x, bj.x), yy1 = fmaxf(bi.y, bj.y);
                float xx2 = fminf(bi.z, bj.z), yy2 = fminf(bi.w, bj.w);
                float w = fmaxf(1e-10f, xx2 - xx1);
                float h = fmaxf(1e-10f, yy2 - yy1);
                float inter = w * h;
                float iou = inter / (ai + aj - inter + 1e-10f);
                bit = (iou > 0.6f) && (labs[j] == li);
            }
            unsigned long long ball = __ballot(bit);
            if (lane == 0) supT[(size_t)c * 1024 + i] = ball;
        }
    }
    __threadfence();                      // release supT before ticket
    __syncthreads();
    if (t == 0) amLast = (atomicAdd(ticket, 1u) == (TOPK_N / 4 - 1)) ? 1u : 0u;
    __syncthreads();
    if (!amLast) return;
    __threadfence();                      // acquire

    // ---- exact greedy NMS, wave 0 of the last block ----
    if (t < 64) {
        unsigned long long kw[16];
        unsigned long long lowmask = (lane == 0) ? 0ull : (~0ull >> (64 - lane));
#pragma unroll
        for (int c = 0; c < 16; ++c) {
            int b = c * 64 + lane;
            bool inb = (b < TOPK_N);
            unsigned long long tmp[16];
#pragma unroll
            for (int w = 0; w <= c; ++w)
                tmp[w] = inb ? supT[(size_t)w * 1024 + b] : 0ull;   // coalesced
            bool v = inb && (val[b] != 0);
            bool ext = false;
#pragma unroll
            for (int w = 0; w < c; ++w) ext = ext || ((tmp[w] & kw[w]) != 0ull);
            unsigned long long m = tmp[c];
            unsigned long long inchunk = m & lowmask;
            bool mykeep;
            if (__ballot(inchunk != 0ull) == 0ull) {
                mykeep = v && !ext;                     // no intra-chunk deps
            } else {
                mykeep = false;
                for (int ii = 0; ii < 64; ++ii) {
                    unsigned long long ball = __ballot(mykeep);
                    if (lane == ii) mykeep = v && !ext && ((ball & inchunk) == 0ull);
                }
            }
            unsigned long long ball2 = __ballot(mykeep);
            kw[c] = ball2;
            if (inb) out_keep[b] = ((ball2 >> lane) & 1ull) ? 1.0f : 0.0f;
        }
    }
}

extern "C" void kernel_launch(void* const* d_in, const int* in_sizes, int n_in,
                              void* d_out, int out_size, void* d_ws, size_t ws_size,
                              hipStream_t stream) {
    const float* cls  = (const float*)d_in[0];
    const float* reg  = (const float*)d_in[1];
    const float* anch = (const float*)d_in[2];
    float* out = (float*)d_out;
    char* ws = (char*)d_ws;

    unsigned* h1r   = (unsigned*)(ws + WS_H1R);
    unsigned* cnt   = (unsigned*)(ws + WS_CNT);
    unsigned* gbin  = (unsigned*)(ws + WS_GBIN);
    unsigned* tick1 = (unsigned*)(ws + WS_TICK1);
    unsigned* tick2 = (unsigned*)(ws + WS_TICK2);
    unsigned long long* cand = (unsigned long long*)(ws + WS_CAND);
    float4* boxes = (float4*)(ws + WS_BOXES);
    int* labs     = (int*)(ws + WS_LABELS);
    int* valid    = (int*)(ws + WS_VALID);
    unsigned long long* supT = (unsigned long long*)(ws + WS_SUP);
    unsigned* mkeys = (unsigned*)(ws + WS_MKEYS);
    unsigned* hred  = (unsigned*)(ws + WS_HRED);

    hipMemsetAsync(ws, 0, WS_MEMSET, stream);

    k_rowmax  <<<M_ANCH / 256, 256, 0, stream>>>(cls, mkeys, h1r);
    k_red_find<<<NBIN / 256, 256, 0, stream>>>(h1r, hred, tick1, gbin);
    k_gather  <<<M_ANCH / (256 * 8), 256, 0, stream>>>((const uint4*)mkeys, gbin, cnt, cand);
    k_rank_decode<<<CAND_CAP / 256, 256, 0, stream>>>(cnt, cand, cls, reg, anch,
                                                      out, boxes, labs, valid);
    k_sup_nms <<<TOPK_N / 4, 256, 0, stream>>>(boxes, labs, supT, tick2,
                                               valid, out + 6 * TOPK_N);
}

// Round 8
// 356.406 us; speedup vs baseline: 1.0349x; 1.0349x over previous
//
#include <hip/hip_runtime.h>
#include <math.h>

#define M_ANCH   589824
#define NCLS     80
#define TOPK_N   1000
#define CAND_CAP 4096
#define NREP     16
#define NBIN     8192          /* 13-bit bins */
#define KSHIFT   19

#define SCALE_CLAMP_F 4.135166556742356f   /* log(1000/16) as f32 */
#define INV_IMG       (1.0f/2048.0f)

// ---------------- ws layout (bytes) ----------------
// [0,      524288)   hist replicas (16 x 8192 u32)  -- memset 0
// [524288, 524292)   cand count (u32)               -- memset 0
// [524292, 524296)   gbin (u32)                     -- memset 0
// [524544, 557312)   cand keys (4096 u64)
// [557312, 573312)   boxes (1000 float4)
// [573312, 577312)   labels (1000 i32)
// [577312, 581312)   valid (1000 i32)
// [581376, 712448)   supT matrix WORD-MAJOR (16 x 1024 u64)
// [712704, 3072000)  mkeys (589824 u32, 16B-aligned)
// [3072000,3104768)  reduced hist (8192 u32)
#define WS_H1R     0
#define WS_CNT     524288
#define WS_GBIN    524292
#define WS_MEMSET  524296
#define WS_CAND    524544
#define WS_BOXES   557312
#define WS_LABELS  573312
#define WS_VALID   577312
#define WS_SUP     581376
#define WS_MKEYS   712704
#define WS_HRED    3072000

// monotone float->uint map (positive floats get top bit set)
__device__ __forceinline__ unsigned fmap(unsigned b) {
    return (b & 0x80000000u) ? ~b : (b | 0x80000000u);
}
__device__ __forceinline__ unsigned funmap(unsigned k) {
    return (k & 0x80000000u) ? (k ^ 0x80000000u) : ~k;
}

// K1 (Design B): dense-coalesced row-max. Block owns 256 rows = 80 KB
// contiguous; chunk-max staged in LDS stride-21; packed 16-bit histogram.
// BW-bound (~30-35 us): two different access designs (r4/r5) timed identical.
__global__ __launch_bounds__(256) void k_rowmax(const float* __restrict__ cls,
                                                unsigned* __restrict__ mkeys,
                                                unsigned* __restrict__ h1r) {
    __shared__ float    cmax[256 * 21];   // 21504 B, stride-21 padded
    __shared__ unsigned lh[NBIN / 2];     // 16384 B packed 2 bins/u32
    int t = threadIdx.x;
    for (int b = t; b < NBIN / 2; b += 256) lh[b] = 0;
    // (lh atomics only happen after the phase-1 barrier below)

    const float4* p = (const float4*)cls + (size_t)blockIdx.x * (256 * 20);
#pragma unroll
    for (int i = 0; i < 20; ++i) {
        float4 v = p[i * 256 + t];
        float c = fmaxf(fmaxf(v.x, v.y), fmaxf(v.z, v.w));
        int cid = i * 256 + t;
        int row = cid / 20;               // compiler magic-mul
        int j   = cid - row * 20;
        cmax[row * 21 + j] = c;
    }
    __syncthreads();

    // phase 2: one row per thread, conflict-free LDS reads (stride 21)
    const float* rp = &cmax[t * 21];
    float m = -INFINITY;
#pragma unroll
    for (int j = 0; j < 20; ++j) m = fmaxf(m, rp[j]);
    unsigned key = fmap(__float_as_uint(m));
    mkeys[blockIdx.x * 256 + t] = key;    // coalesced 1 KB/block
    unsigned bin = key >> KSHIFT;
    atomicAdd(&lh[bin >> 1], 1u << ((bin & 1) << 4));
    __syncthreads();

    unsigned rep = (blockIdx.x & (NREP - 1)) * NBIN;
    for (int b2 = t; b2 < NBIN / 2; b2 += 256) {
        unsigned c = lh[b2];
        unsigned c0 = c & 0xFFFFu, c1 = c >> 16;
        if (c0) atomicAdd(&h1r[rep + 2 * b2], c0);
        if (c1) atomicAdd(&h1r[rep + 2 * b2 + 1], c1);
    }
}

// K1b: parallel replica reduction, 32 blocks. Replaces the single-CU 512 KB
// read that dominated k_find (~20 us at ~25 GB/s/CU) with a multi-CU read.
__global__ __launch_bounds__(256) void k_red(const unsigned* __restrict__ h1r,
                                             unsigned* __restrict__ hred) {
    int b = blockIdx.x * 256 + threadIdx.x;   // 32*256 = 8192 bins
    unsigned s = 0;
#pragma unroll
    for (int r = 0; r < NREP; ++r) s += h1r[r * NBIN + b];
    hred[b] = s;
}

// K2: find 13-bit bin B of the 1000th-largest key from the reduced hist;
// gather threshold = B-1 (tie-safety margin).
__global__ __launch_bounds__(1024) void k_find(const unsigned* __restrict__ hred,
                                               unsigned* __restrict__ gbin) {
    __shared__ unsigned hist[NBIN];
    __shared__ unsigned csum[256];
    int t = threadIdx.x;
    for (int b = t; b < NBIN; b += 1024) hist[b] = hred[b];
    __syncthreads();
    if (t < 256) {
        unsigned cs = 0;
        for (int k = 0; k < 32; ++k) cs += hist[t * 32 + k];
        csum[t] = cs;
    }
    __syncthreads();
    if (t == 0) {
        unsigned cum = 0, above = 0;
        int C = 0;
        for (int c = 255; c >= 0; --c) {
            if (cum + csum[c] >= TOPK_N || c == 0) { C = c; above = cum; break; }
            cum += csum[c];
        }
        int B = C * 32;
        unsigned cum2 = above;
        for (int b = C * 32 + 31; b >= C * 32; --b) {
            cum2 += hist[b];
            if (cum2 >= TOPK_N) { B = b; break; }
            if (b == C * 32) B = b;
        }
        *gbin = (B >= 1) ? (unsigned)(B - 1) : 0u;
    }
}

// K3: gather candidates above threshold as (score_bits<<32)|~idx.
__global__ __launch_bounds__(256) void k_gather(const uint4* __restrict__ mk4,
                                                const unsigned* __restrict__ gbin,
                                                unsigned* __restrict__ cnt,
                                                unsigned long long* __restrict__ cand) {
    int tid = blockIdx.x * 256 + threadIdx.x;
    unsigned gb = *gbin;
    uint4 a = mk4[tid * 2];
    uint4 b4 = mk4[tid * 2 + 1];
    unsigned keys[8] = {a.x, a.y, a.z, a.w, b4.x, b4.y, b4.z, b4.w};
    int lc = 0;
    unsigned sel[8];
#pragma unroll
    for (int q = 0; q < 8; ++q)
        if ((keys[q] >> KSHIFT) >= gb) sel[lc++] = (unsigned)q;
    if (lc) {
        unsigned base = atomicAdd(cnt, (unsigned)lc);
        for (int q = 0; q < lc; ++q) {
            unsigned pos = base + (unsigned)q;
            if (pos < CAND_CAP) {
                unsigned i = (unsigned)tid * 8u + sel[q];
                float m = __uint_as_float(funmap(keys[sel[q]]));
                // emulate np float32 sigmoid pipeline (correctly-rounded exp):
                float e = (float)exp(-(double)m);
                float sc = 1.0f / (1.0f + e);
                cand[pos] = ((unsigned long long)__float_as_uint(sc) << 32)
                            | (unsigned)(~i);
            }
        }
    }
}

// K4: rank-by-count (keys unique) + direct decode into output slot.
__global__ __launch_bounds__(256) void k_rank_decode(const unsigned* __restrict__ cnt,
                                                     const unsigned long long* __restrict__ cand,
                                                     const float* __restrict__ cls,
                                                     const float* __restrict__ reg,
                                                     const float* __restrict__ anch,
                                                     float* __restrict__ out,
                                                     float4* __restrict__ boxes_ws,
                                                     int* __restrict__ lab_ws,
                                                     int* __restrict__ val_ws) {
    __shared__ unsigned long long sh[CAND_CAP];   // 32 KiB
    int t = threadIdx.x;
    unsigned n = *cnt;
    if (n > CAND_CAP) n = CAND_CAP;
    for (int k = t; k < (int)n; k += 256) sh[k] = cand[k];
    __syncthreads();
    int k = blockIdx.x * 256 + t;
    if (k >= (int)n) return;
    unsigned long long key = sh[k];
    int rank = 0;
    for (int j = 0; j < (int)n; ++j) rank += (sh[j] > key) ? 1 : 0;
    if (rank >= TOPK_N) return;
    int r = rank;
    unsigned idx = ~(unsigned)(key & 0xFFFFFFFFull);
    float sc = __uint_as_float((unsigned)(key >> 32));
    // label = argmax (first max wins, matching np.argmax), float4 loads
    const float4* rowp = (const float4*)(cls + (size_t)idx * NCLS);
    float best = -INFINITY;
    int lbl = 0;
#pragma unroll
    for (int c4 = 0; c4 < 20; ++c4) {
        float4 v = rowp[c4];
        if (v.x > best) { best = v.x; lbl = c4 * 4; }
        if (v.y > best) { best = v.y; lbl = c4 * 4 + 1; }
        if (v.z > best) { best = v.z; lbl = c4 * 4 + 2; }
        if (v.w > best) { best = v.w; lbl = c4 * 4 + 3; }
    }
    float4 rg = ((const float4*)reg)[idx];
    float4 an = ((const float4*)anch)[idx];
    float ox = fminf(fmaxf(rg.x * an.z, -32.0f), 32.0f);
    float oy = fminf(fmaxf(rg.y * an.w, -32.0f), 32.0f);
    float cx = an.x + ox, cy = an.y + oy;
    float w = an.z * expf(fminf(rg.z, SCALE_CLAMP_F));
    float h = an.w * expf(fminf(rg.w, SCALE_CLAMP_F));
    float x1 = fminf(fmaxf((cx - 0.5f * w) * INV_IMG, 0.0f), 1.0f);
    float y1 = fminf(fmaxf((cy - 0.5f * h) * INV_IMG, 0.0f), 1.0f);
    float x2 = fminf(fmaxf((cx + 0.5f * w) * INV_IMG, 0.0f), 1.0f);
    float y2 = fminf(fmaxf((cy + 0.5f * h) * INV_IMG, 0.0f), 1.0f);
    out[r * 4 + 0] = x1;
    out[r * 4 + 1] = y1;
    out[r * 4 + 2] = x2;
    out[r * 4 + 3] = y2;
    out[4 * TOPK_N + r] = sc;
    out[5 * TOPK_N + r] = (float)lbl;
    boxes_ws[r] = make_float4(x1, y1, x2, y2);
    lab_ws[r] = lbl;
    val_ws[r] = (sc >= 0.05f) ? 1 : 0;
}

// K5: suppression bitmask matrix, WORD-MAJOR layout supT[w*1024 + i].
// 250 blocks x 256 threads, one wave per row (4 rows/block). Lower triangle.
__global__ __launch_bounds__(256) void k_sup(const float4* __restrict__ boxes,
                                             const int* __restrict__ labs,
                                             unsigned long long* __restrict__ supT) {
    int i = blockIdx.x * 4 + (threadIdx.x >> 6);
    int lane = threadIdx.x & 63;
    if (i >= TOPK_N) return;
    int cmax = i >> 6;
    float4 bi = boxes[i];
    float ai = (bi.z - bi.x) * (bi.w - bi.y);
    int li = labs[i];
    for (int c = 0; c <= cmax; ++c) {
        int j = c * 64 + lane;
        bool bit = false;
        if (j < TOPK_N) {
            float4 bj = boxes[j];
            float aj = (bj.z - bj.x) * (bj.w - bj.y);
            float xx1 = fmaxf(bi.x, bj.x), yy1 = fmaxf(bi.y, bj.y);
            float xx2 = fminf(bi.z, bj.z), yy2 = fminf(bi.w, bj.w);
            float w = fmaxf(1e-10f, xx2 - xx1);
            float h = fmaxf(1e-10f, yy2 - yy1);
            float inter = w * h;
            float iou = inter / (ai + aj - inter + 1e-10f);
            bit = (iou > 0.6f) && (labs[j] == li);
        }
        unsigned long long ball = __ballot(bit);
        if (lane == 0) supT[(size_t)c * 1024 + i] = ball;
    }
}

// K6: exact greedy NMS, single wave. Word-major supT -> coalesced batches.
__global__ __launch_bounds__(64) void k_nms(const unsigned long long* __restrict__ supT,
                                            const int* __restrict__ val,
                                            float* __restrict__ out_keep) {
    int lane = threadIdx.x;
    unsigned long long kw[16];
    unsigned long long lowmask = (lane == 0) ? 0ull : (~0ull >> (64 - lane));
#pragma unroll
    for (int c = 0; c < 16; ++c) {
        int b = c * 64 + lane;
        bool inb = (b < TOPK_N);
        unsigned long long tmp[16];
#pragma unroll
        for (int w = 0; w <= c; ++w)
            tmp[w] = inb ? supT[(size_t)w * 1024 + b] : 0ull;   // coalesced batch
        bool v = inb && (val[b] != 0);
        bool ext = false;
#pragma unroll
        for (int w = 0; w < c; ++w) ext = ext || ((tmp[w] & kw[w]) != 0ull);
        unsigned long long m = tmp[c];
        unsigned long long inchunk = m & lowmask;
        bool mykeep;
        if (__ballot(inchunk != 0ull) == 0ull) {
            mykeep = v && !ext;                     // no intra-chunk deps
        } else {
            mykeep = false;
            for (int i = 0; i < 64; ++i) {
                unsigned long long ball = __ballot(mykeep);
                if (lane == i) mykeep = v && !ext && ((ball & inchunk) == 0ull);
            }
        }
        unsigned long long ball2 = __ballot(mykeep);
        kw[c] = ball2;
        if (inb) out_keep[b] = ((ball2 >> lane) & 1ull) ? 1.0f : 0.0f;
    }
}

extern "C" void kernel_launch(void* const* d_in, const int* in_sizes, int n_in,
                              void* d_out, int out_size, void* d_ws, size_t ws_size,
                              hipStream_t stream) {
    const float* cls  = (const float*)d_in[0];
    const float* reg  = (const float*)d_in[1];
    const float* anch = (const float*)d_in[2];
    float* out = (float*)d_out;
    char* ws = (char*)d_ws;

    unsigned* h1r  = (unsigned*)(ws + WS_H1R);
    unsigned* cnt  = (unsigned*)(ws + WS_CNT);
    unsigned* gbin = (unsigned*)(ws + WS_GBIN);
    unsigned long long* cand = (unsigned long long*)(ws + WS_CAND);
    float4* boxes = (float4*)(ws + WS_BOXES);
    int* labs     = (int*)(ws + WS_LABELS);
    int* valid    = (int*)(ws + WS_VALID);
    unsigned long long* supT = (unsigned long long*)(ws + WS_SUP);
    unsigned* mkeys = (unsigned*)(ws + WS_MKEYS);
    unsigned* hred  = (unsigned*)(ws + WS_HRED);

    hipMemsetAsync(ws, 0, WS_MEMSET, stream);

    k_rowmax<<<M_ANCH / 256, 256, 0, stream>>>(cls, mkeys, h1r);
    k_red   <<<NBIN / 256, 256, 0, stream>>>(h1r, hred);
    k_find  <<<1, 1024, 0, stream>>>(hred, gbin);
    k_gather<<<M_ANCH / (256 * 8), 256, 0, stream>>>((const uint4*)mkeys, gbin, cnt, cand);
    k_rank_decode<<<CAND_CAP / 256, 256, 0, stream>>>(cnt, cand, cls, reg, anch,
                                                      out, boxes, labs, valid);
    k_sup   <<<TOPK_N / 4, 256, 0, stream>>>(boxes, labs, supT);
    k_nms   <<<1, 64, 0, stream>>>(supT, valid, out + 6 * TOPK_N);
}